// Round 18
// baseline (288.362 us; speedup 1.0000x reference)
//
#include <hip/hip_runtime.h>
#include <stdint.h>

typedef unsigned short u16;
typedef __bf16 bf16x8 __attribute__((ext_vector_type(8)));
typedef float f32x4v __attribute__((ext_vector_type(4)));

#define BB 8
#define SS 2048
#define TT 2048
#define DD 1024
#define LN_EPS 1e-5f

__device__ __forceinline__ float sigm(float x){ return 1.f/(1.f+__expf(-x)); }

__device__ __forceinline__ u16 f2bf(float v){
  uint32_t x = __builtin_bit_cast(uint32_t, v);
  uint32_t r = x + 0x7fffu + ((x >> 16) & 1u);
  return (u16)(r >> 16);
}
__device__ __forceinline__ float bf2f(u16 u){
  return __builtin_bit_cast(float, (uint32_t)u << 16);
}

__device__ __forceinline__ void gload16(const void* g, void* l){
  __builtin_amdgcn_global_load_lds((const __attribute__((address_space(1))) unsigned int*)g,
                                   (__attribute__((address_space(3))) unsigned int*)l, 16, 0, 0);
}

__device__ __forceinline__ int xcd_swizzle(int orig, int nwg){
  int q = nwg >> 3, r = nwg & 7;
  int xcd = orig & 7, idx = orig >> 3;
  return (xcd < r ? xcd*(q+1) : r*(q+1) + (xcd-r)*q) + idx;
}

// ---------------- prep: sv[d] = sigm(Wov[d]·sigm(vs)+bov[d]) * tanh(Wov[D+d]·sigm(vs)+bov[D+d]) ----
__global__ __launch_bounds__(256) void prep_sv(const float* __restrict__ Wov, const float* __restrict__ bov,
                        const float* __restrict__ vs, float* __restrict__ sv){
  int d = blockIdx.x, tid = threadIdx.x;
  float a = 0.f, b = 0.f;
  for (int j = tid; j < DD; j += 256){
    float s = sigm(vs[j]);
    a += Wov[(size_t)d*DD + j]*s;
    b += Wov[(size_t)(d+DD)*DD + j]*s;
  }
  #pragma unroll
  for (int o = 32; o; o >>= 1){ a += __shfl_xor(a,o); b += __shfl_xor(b,o); }
  __shared__ float sa[4], sb[4];
  int lane = tid & 63, w = tid >> 6;
  if (!lane){ sa[w] = a; sb[w] = b; }
  __syncthreads();
  if (tid == 0){
    float A = sa[0]+sa[1]+sa[2]+sa[3] + bov[d];
    float Bv= sb[0]+sb[1]+sb[2]+sb[3] + bov[DD+d];
    sv[d] = sigm(A) * tanhf(Bv);
  }
}

// ---- fused prep: region A = scale_kv_transpose (4096 blocks), B = cvt X/Wq (4096), C = mask pack (512)
__global__ __launch_bounds__(256) void prep_fused(
    const float* __restrict__ Y, const float* __restrict__ ks, const float* __restrict__ sv,
    u16* __restrict__ kbf, u16* __restrict__ vT,
    const float* __restrict__ X, u16* __restrict__ Xbf,
    const float* __restrict__ Wq, u16* __restrict__ Wqbf,
    const int* __restrict__ mask, uint32_t* __restrict__ m32)
{
  __shared__ float tile[64][65];
  const int id = blockIdx.x, tid = threadIdx.x;
  if (id < 4096){
    // ---- scale_kv_transpose: x=id&31 (t-tile), y=(id>>5)&15 (d-tile), z=id>>9 (batch)
    int tx = tid & 15, ty = tid >> 4;
    int b = id >> 9;
    int t0 = (id & 31)*64, d0 = ((id >> 5) & 15)*64;
    const float* Yb = Y + ((size_t)b*TT + t0)*DD + d0;
    u16* kb = kbf + ((size_t)b*TT + t0)*DD + d0;
    float4 s = *(const float4*)(sv + d0 + tx*4);
    float4 k4 = *(const float4*)(ks + d0 + tx*4);
    k4.x = sigm(k4.x); k4.y = sigm(k4.y); k4.z = sigm(k4.z); k4.w = sigm(k4.w);
    #pragma unroll
    for (int it = 0; it < 4; ++it){
      int t = ty + it*16;
      float4 y = *(const float4*)(Yb + (size_t)t*DD + tx*4);
      ushort4 ko;
      ko.x = f2bf(y.x*k4.x); ko.y = f2bf(y.y*k4.y); ko.z = f2bf(y.z*k4.z); ko.w = f2bf(y.w*k4.w);
      *(ushort4*)(kb + (size_t)t*DD + tx*4) = ko;
      tile[t][tx*4+0] = y.x*s.x; tile[t][tx*4+1] = y.y*s.y;
      tile[t][tx*4+2] = y.z*s.z; tile[t][tx*4+3] = y.w*s.w;
    }
    __syncthreads();
    u16* ob = vT + ((size_t)b*DD + d0)*TT + t0;
    #pragma unroll
    for (int it = 0; it < 4; ++it){
      int dd = ty + it*16;
      ushort4 o;
      o.x = f2bf(tile[tx*4+0][dd]); o.y = f2bf(tile[tx*4+1][dd]);
      o.z = f2bf(tile[tx*4+2][dd]); o.w = f2bf(tile[tx*4+3][dd]);
      *(ushort4*)(ob + (size_t)dd*TT + tx*4) = o;
    }
  } else if (id < 8192){
    // ---- cvt f32->bf16 for X then Wq, grid-stride over 4096 blocks
    const int n1 = BB*SS*DD, n2 = DD*DD, n = n1 + n2;
    const int bid = id - 4096;
    for (int i = (bid*256 + tid)*4; i < n; i += 4096*256*4){
      const float* s; u16* d; int j;
      if (i < n1){ s = X; d = Xbf; j = i; } else { s = Wq; d = Wqbf; j = i - n1; }
      float4 v = *(const float4*)(s + j);
      ushort4 o; o.x = f2bf(v.x); o.y = f2bf(v.y); o.z = f2bf(v.z); o.w = f2bf(v.w);
      *(ushort4*)(d + j) = o;
    }
  } else {
    // ---- mask pack: 512 blocks
    int idx = (id - 8192)*256 + tid;
    const int* mp = mask + ((size_t)(idx >> 6))*TT + (idx & 63)*32;
    uint32_t b = 0;
    #pragma unroll
    for (int j = 0; j < 8; ++j){
      int4 v = *(const int4*)(mp + j*4);
      b |= (uint32_t)(v.x != 0) << (j*4+0);
      b |= (uint32_t)(v.y != 0) << (j*4+1);
      b |= (uint32_t)(v.z != 0) << (j*4+2);
      b |= (uint32_t)(v.w != 0) << (j*4+3);
    }
    m32[idx] = b;
  }
}

// ------- 256x256 GEMM, BK=64, 4-phase max-lead counted-vmcnt pipeline (verified) -------
// OUTMODE: 3=bf16 exp+mask (QK^T), 4=bf16 row-normalized (PV)
template<int OUTMODE>
__global__ __launch_bounds__(512, 1)
void gemm256_bt(const u16* __restrict__ A, const u16* __restrict__ B,
                void* __restrict__ Cv, const float* __restrict__ bias,
                const uint32_t* __restrict__ mpk,
                int K, int lda, int ldb, int ldc,
                size_t sA, size_t sB, size_t sC, int ntx, int ntxty, int nwg)
{
  __shared__ __align__(16) u16 As[2][16384];
  __shared__ __align__(16) u16 Bs[2][16384];
  __shared__ float Lsum[256];
  const int tid = threadIdx.x, lane = tid & 63, w = tid >> 6;
  const int wm = w >> 2, wn = w & 3;
  const int sw = xcd_swizzle(blockIdx.x, nwg);
  const int bz_ = sw / ntxty;
  const int rem = sw - bz_*ntxty;
  const int by = rem / ntx, bx = rem - (rem/ntx)*ntx;
  const size_t bz = bz_;
  const int tM = by*256, tN = bx*256;
  const u16* Ab = A + bz*sA;
  const u16* Bb = B + bz*sB;
  const int NT = K >> 6;

  const int srow  = lane >> 3;
  const int sslot = (lane & 7) ^ srow;
  const int frow  = lane & 15;
  const int fs    = lane >> 4;
  const int fx    = lane & 7;

#define BAR() asm volatile("s_barrier" ::: "memory")
#define WAITV(n) asm volatile("s_waitcnt vmcnt(" #n ")" ::: "memory")

#define STAGE(h) do { \
    const int tau_ = (h) >> 2, typ_ = (h) & 3; \
    const int buf_ = tau_ & 1, hi_ = typ_ >> 1, k0_ = tau_ << 6; \
    const u16* src_; int ld_, t0_; u16* dst_; \
    if ((typ_ & 1) == 0){ src_ = Ab; ld_ = lda; t0_ = tM; dst_ = &As[buf_][hi_*8192]; } \
    else                { src_ = Bb; ld_ = ldb; t0_ = tN; dst_ = &Bs[buf_][hi_*8192]; } \
    _Pragma("unroll") \
    for (int i_ = 0; i_ < 2; ++i_){ \
      const int chunk_ = w*2 + i_; \
      gload16(src_ + (size_t)(t0_ + hi_*128 + chunk_*8 + srow)*ld_ + (k0_ + sslot*8), \
              dst_ + chunk_*512); \
    } } while(0)

#define READA(buf, mh, a) do { \
    _Pragma("unroll") for (int m_ = 0; m_ < 4; ++m_) \
    _Pragma("unroll") for (int ks_ = 0; ks_ < 2; ++ks_) \
      a[m_*2+ks_] = *(const bf16x8*)&As[buf][(wm*128 + (mh)*64 + m_*16 + frow)*64 + ((ks_*4+fs)^fx)*8]; \
  } while(0)
#define READB(buf, nh, b) do { \
    _Pragma("unroll") for (int n_ = 0; n_ < 2; ++n_) \
    _Pragma("unroll") for (int ks_ = 0; ks_ < 2; ++ks_) \
      b[n_*2+ks_] = *(const bf16x8*)&Bs[buf][(wn*64 + (nh)*32 + n_*16 + frow)*64 + ((ks_*4+fs)^fx)*8]; \
  } while(0)
#define QUAD(mh, nh, a, b) do { \
    __builtin_amdgcn_s_setprio(1); \
    _Pragma("unroll") for (int m_ = 0; m_ < 4; ++m_) \
    _Pragma("unroll") for (int n_ = 0; n_ < 2; ++n_) \
    _Pragma("unroll") for (int ks_ = 0; ks_ < 2; ++ks_) \
      acc[(mh)*4+m_][(nh)*2+n_] = __builtin_amdgcn_mfma_f32_16x16x32_bf16( \
          a[m_*2+ks_], b[n_*2+ks_], acc[(mh)*4+m_][(nh)*2+n_], 0, 0, 0); \
    __builtin_amdgcn_s_setprio(0); \
  } while(0)
#define LSUM(mh, a) do { \
    if (OUTMODE == 4 && wn == (mh)){ \
      _Pragma("unroll") for (int m_ = 0; m_ < 4; ++m_){ \
        acc_l[m_] = __builtin_amdgcn_mfma_f32_16x16x32_bf16(a[m_*2],   vone, acc_l[m_], 0, 0, 0); \
        acc_l[m_] = __builtin_amdgcn_mfma_f32_16x16x32_bf16(a[m_*2+1], vone, acc_l[m_], 0, 0, 0); \
      } \
    } } while(0)

  f32x4v acc[8][4];
  #pragma unroll
  for (int m = 0; m < 8; ++m)
    #pragma unroll
    for (int n = 0; n < 4; ++n) acc[m][n] = (f32x4v){0.f,0.f,0.f,0.f};

  f32x4v acc_l[4];
  bf16x8 vone;
  #pragma unroll
  for (int m = 0; m < 4; ++m) acc_l[m] = (f32x4v){0.f,0.f,0.f,0.f};
  #pragma unroll
  for (int i = 0; i < 8; ++i) vone[i] = (__bf16)1.0f;

  #pragma unroll
  for (int h = 0; h < 8; ++h) STAGE(h);

  bf16x8 a0[8], a1[8], b0[4], b1[4];

  for (int t = 0; t < NT; ++t){
    const int buf = t & 1;
    const int nx = t + 2;
    if (t == NT-1) { WAITV(0); } else { WAITV(8); }
    BAR();
    READA(buf, 0, a0);
    READB(buf, 0, b0);
    QUAD(0, 0, a0, b0);
    LSUM(0, a0);
    BAR();
    READB(buf, 1, b1);
    QUAD(0, 1, a0, b1);
    BAR();
    READA(buf, 1, a1);
    if (nx < NT){ STAGE(nx*4+1); STAGE(nx*4+3); }
    QUAD(1, 1, a1, b1);
    LSUM(1, a1);
    BAR();
    if (nx < NT){ STAGE(nx*4+0); STAGE(nx*4+2); }
    QUAD(1, 0, a1, b0);
  }

  const int erow = (lane >> 4) * 4;
  const int ecol = lane & 15;

  if (OUTMODE == 4){
    if (wn < 2 && ecol == 0){
      #pragma unroll
      for (int m = 0; m < 4; ++m)
        #pragma unroll
        for (int r = 0; r < 4; ++r)
          Lsum[wm*128 + wn*64 + m*16 + erow + r] = acc_l[m][r];
    }
    __syncthreads();
  }

  #pragma unroll
  for (int m = 0; m < 8; ++m){
    float li[4];
    if (OUTMODE == 4){
      #pragma unroll
      for (int r = 0; r < 4; ++r) li[r] = 1.f / Lsum[wm*128 + m*16 + erow + r];
    }
    #pragma unroll
    for (int n = 0; n < 4; ++n){
      const int row0 = tM + wm*128 + m*16 + erow;
      const int col  = tN + wn*64  + n*16 + ecol;
      if (OUTMODE == 4){
        u16* C = (u16*)Cv + bz*sC;
        #pragma unroll
        for (int r = 0; r < 4; ++r) C[(size_t)(row0+r)*ldc + col] = f2bf(acc[m][n][r] * li[r]);
      } else {
        u16* C = (u16*)Cv + bz*sC;
        const int c32 = (tN + wn*64 + n*16) >> 5;
        #pragma unroll
        for (int r = 0; r < 4; ++r){
          const int row = row0 + r;
          const uint32_t mb = mpk[(size_t)row*64 + c32];
          float e = ((mb >> (col & 31)) & 1u) ? __expf(acc[m][n][r]) : 0.f;
          C[(size_t)row*ldc + col] = f2bf(e);
        }
      }
    }
  }
#undef STAGE
#undef READA
#undef READB
#undef QUAD
#undef LSUM
#undef BAR
#undef WAITV
}

// ------- 128x128 GEMM, BK=64, same 4-phase dbuf pipeline, 4 waves (verified) -------
template<int OUTMODE>
__global__ __launch_bounds__(256, 1)
void gemm128_bt(const u16* __restrict__ A, const u16* __restrict__ B,
                void* __restrict__ Cv, const float* __restrict__ bias,
                int K, int lda, int ldb, int ldc, int ntx, int nwg)
{
  __shared__ __align__(16) u16 As[2][8192];
  __shared__ __align__(16) u16 Bs[2][8192];
  const int tid = threadIdx.x, lane = tid & 63, w = tid >> 6;
  const int wm = w >> 1, wn = w & 1;
  const int sw = xcd_swizzle(blockIdx.x, nwg);
  const int by = sw / ntx, bx = sw - (sw/ntx)*ntx;
  const int tM = by*128, tN = bx*128;
  const int NT = K >> 6;

  const int srow  = lane >> 3;
  const int sslot = (lane & 7) ^ srow;
  const int frow  = lane & 15;
  const int fs    = lane >> 4;
  const int fx    = lane & 7;

#define BAR() asm volatile("s_barrier" ::: "memory")
#define WAITV(n) asm volatile("s_waitcnt vmcnt(" #n ")" ::: "memory")

#define STAGE(h) do { \
    const int tau_ = (h) >> 2, typ_ = (h) & 3; \
    const int buf_ = tau_ & 1, hi_ = typ_ >> 1, k0_ = tau_ << 6; \
    const u16* src_; int ld_, t0_; u16* dst_; \
    if ((typ_ & 1) == 0){ src_ = A; ld_ = lda; t0_ = tM; dst_ = &As[buf_][hi_*4096]; } \
    else                { src_ = B; ld_ = ldb; t0_ = tN; dst_ = &Bs[buf_][hi_*4096]; } \
    _Pragma("unroll") \
    for (int i_ = 0; i_ < 2; ++i_){ \
      const int chunk_ = w*2 + i_; \
      gload16(src_ + (size_t)(t0_ + hi_*64 + chunk_*8 + srow)*ld_ + (k0_ + sslot*8), \
              dst_ + chunk_*512); \
    } } while(0)

#define READA(buf, mh, a) do { \
    _Pragma("unroll") for (int m_ = 0; m_ < 2; ++m_) \
    _Pragma("unroll") for (int ks_ = 0; ks_ < 2; ++ks_) \
      a[m_*2+ks_] = *(const bf16x8*)&As[buf][(wm*64 + (mh)*32 + m_*16 + frow)*64 + ((ks_*4+fs)^fx)*8]; \
  } while(0)
#define READB(buf, nh, b) do { \
    _Pragma("unroll") for (int n_ = 0; n_ < 2; ++n_) \
    _Pragma("unroll") for (int ks_ = 0; ks_ < 2; ++ks_) \
      b[n_*2+ks_] = *(const bf16x8*)&Bs[buf][(wn*64 + (nh)*32 + n_*16 + frow)*64 + ((ks_*4+fs)^fx)*8]; \
  } while(0)
#define QUAD(mh, nh, a, b) do { \
    __builtin_amdgcn_s_setprio(1); \
    _Pragma("unroll") for (int m_ = 0; m_ < 2; ++m_) \
    _Pragma("unroll") for (int n_ = 0; n_ < 2; ++n_) \
    _Pragma("unroll") for (int ks_ = 0; ks_ < 2; ++ks_) \
      acc[(mh)*2+m_][(nh)*2+n_] = __builtin_amdgcn_mfma_f32_16x16x32_bf16( \
          a[m_*2+ks_], b[n_*2+ks_], acc[(mh)*2+m_][(nh)*2+n_], 0, 0, 0); \
    __builtin_amdgcn_s_setprio(0); \
  } while(0)

  f32x4v acc[4][4];
  #pragma unroll
  for (int m = 0; m < 4; ++m)
    #pragma unroll
    for (int n = 0; n < 4; ++n) acc[m][n] = (f32x4v){0.f,0.f,0.f,0.f};

  #pragma unroll
  for (int h = 0; h < 8; ++h) STAGE(h);

  bf16x8 a0[4], a1[4], b0[4], b1[4];

  for (int t = 0; t < NT; ++t){
    const int buf = t & 1;
    const int nx = t + 2;
    if (t == NT-1) { WAITV(0); } else { WAITV(8); }
    BAR();
    READA(buf, 0, a0);
    READB(buf, 0, b0);
    QUAD(0, 0, a0, b0);
    BAR();
    READB(buf, 1, b1);
    QUAD(0, 1, a0, b1);
    BAR();
    READA(buf, 1, a1);
    if (nx < NT){ STAGE(nx*4+1); STAGE(nx*4+3); }
    QUAD(1, 1, a1, b1);
    BAR();
    if (nx < NT){ STAGE(nx*4+0); STAGE(nx*4+2); }
    QUAD(1, 0, a1, b0);
  }

  const int erow = (lane >> 4) * 4;
  const int ecol = lane & 15;
  #pragma unroll
  for (int m = 0; m < 4; ++m){
    #pragma unroll
    for (int n = 0; n < 4; ++n){
      const int row0 = tM + wm*64 + m*16 + erow;
      const int col  = tN + wn*64 + n*16 + ecol;
      float bv = (OUTMODE == 2) ? bias[col] : 0.f;
      u16* C = (u16*)Cv;
      #pragma unroll
      for (int r = 0; r < 4; ++r) C[(size_t)(row0+r)*ldc + col] = f2bf(acc[m][n][r] + bv);
    }
  }
#undef STAGE
#undef READA
#undef READB
#undef QUAD
#undef BAR
#undef WAITV
}

// ---------------- per-wave LN on q rows (bf16 in-place), sigm(qs) inline ----------------
__global__ __launch_bounds__(256) void ln_q(u16* __restrict__ qb, const float* __restrict__ g1,
                     const float* __restrict__ b1, const float* __restrict__ qs){
  const int w = threadIdx.x >> 6, lane = threadIdx.x & 63;
  const size_t r = (size_t)blockIdx.x * 4 + w;
  u16* row = qb + r * DD;
  uint4 v0 = *(const uint4*)(row + lane*16);
  uint4 v1 = *(const uint4*)(row + lane*16 + 8);
  const u16* vp0 = (const u16*)&v0;
  const u16* vp1 = (const u16*)&v1;
  float x[16];
  #pragma unroll
  for (int i = 0; i < 8; ++i){ x[i] = bf2f(vp0[i]); x[8+i] = bf2f(vp1[i]); }
  float s = 0.f, ss = 0.f;
  #pragma unroll
  for (int i = 0; i < 16; ++i){ s += x[i]; ss += x[i]*x[i]; }
  #pragma unroll
  for (int o = 32; o; o >>= 1){ s += __shfl_xor(s,o); ss += __shfl_xor(ss,o); }
  float mean = s * (1.f/DD);
  float var  = ss * (1.f/DD) - mean*mean;
  float rs = rsqrtf(var + LN_EPS);
  uint4 o0, o1;
  u16* op0 = (u16*)&o0; u16* op1 = (u16*)&o1;
  #pragma unroll
  for (int j = 0; j < 4; ++j){
    float4 g = *(const float4*)(g1 + lane*16 + j*4);
    float4 b = *(const float4*)(b1 + lane*16 + j*4);
    float4 q = *(const float4*)(qs + lane*16 + j*4);
    q.x = sigm(q.x); q.y = sigm(q.y); q.z = sigm(q.z); q.w = sigm(q.w);
    u16* op = (j < 2) ? (op0 + j*4) : (op1 + (j-2)*4);
    op[0] = f2bf(((x[j*4+0]-mean)*rs*g.x + b.x) * q.x * 0.03125f);
    op[1] = f2bf(((x[j*4+1]-mean)*rs*g.y + b.y) * q.y * 0.03125f);
    op[2] = f2bf(((x[j*4+2]-mean)*rs*g.z + b.z) * q.z * 0.03125f);
    op[3] = f2bf(((x[j*4+3]-mean)*rs*g.w + b.w) * q.w * 0.03125f);
  }
  *(uint4*)(row + lane*16) = o0;
  *(uint4*)(row + lane*16 + 8) = o1;
}

// ------- per-wave final LN: reads Xbf (bf16) + obf (bf16), writes d_out f32 once -------
__global__ __launch_bounds__(256) void final_ln(const u16* __restrict__ Xbf, const u16* __restrict__ obf,
                         float* __restrict__ out,
                         const float* __restrict__ g2, const float* __restrict__ b2){
  const int w = threadIdx.x >> 6, lane = threadIdx.x & 63;
  const size_t r = (size_t)blockIdx.x * 4 + w;
  const u16* xr = Xbf + r * DD;
  const u16* orr = obf + r * DD;
  float* orw = out + r * DD;
  uint4 xv0 = *(const uint4*)(xr + lane*16);
  uint4 xv1 = *(const uint4*)(xr + lane*16 + 8);
  uint4 ov0 = *(const uint4*)(orr + lane*16);
  uint4 ov1 = *(const uint4*)(orr + lane*16 + 8);
  const u16* xp0 = (const u16*)&xv0;
  const u16* xp1 = (const u16*)&xv1;
  const u16* op0 = (const u16*)&ov0;
  const u16* op1 = (const u16*)&ov1;
  float z[16];
  float s = 0.f, ss = 0.f;
  #pragma unroll
  for (int i = 0; i < 8; ++i){
    z[i]   = bf2f(xp0[i]) + bf2f(op0[i]);
    z[8+i] = bf2f(xp1[i]) + bf2f(op1[i]);
  }
  #pragma unroll
  for (int i = 0; i < 16; ++i){ s += z[i]; ss += z[i]*z[i]; }
  #pragma unroll
  for (int o = 32; o; o >>= 1){ s += __shfl_xor(s,o); ss += __shfl_xor(ss,o); }
  float mean = s * (1.f/DD);
  float var  = ss * (1.f/DD) - mean*mean;
  float rs = rsqrtf(var + LN_EPS);
  #pragma unroll
  for (int j = 0; j < 4; ++j){
    float4 g = *(const float4*)(g2 + lane*16 + j*4);
    float4 b = *(const float4*)(b2 + lane*16 + j*4);
    float4 o;
    o.x = (z[j*4+0]-mean)*rs*g.x + b.x;
    o.y = (z[j*4+1]-mean)*rs*g.y + b.y;
    o.z = (z[j*4+2]-mean)*rs*g.z + b.z;
    o.w = (z[j*4+3]-mean)*rs*g.w + b.w;
    *(float4*)(orw + lane*16 + j*4) = o;
  }
}

extern "C" void kernel_launch(void* const* d_in, const int* in_sizes, int n_in,
                              void* d_out, int out_size, void* d_ws, size_t ws_size,
                              hipStream_t stream)
{
  const float* X  = (const float*)d_in[0];
  const float* Y  = (const float*)d_in[1];
  const float* qs = (const float*)d_in[2];
  const float* ks = (const float*)d_in[3];
  const float* vs = (const float*)d_in[4];
  const float* Wq = (const float*)d_in[5];
  const float* bq = (const float*)d_in[6];
  const float* g1 = (const float*)d_in[7];
  const float* b1 = (const float*)d_in[8];
  const float* Wov= (const float*)d_in[9];
  const float* bov= (const float*)d_in[10];
  const float* g2 = (const float*)d_in[11];
  const float* b2 = (const float*)d_in[12];
  const int* mask = (const int*)d_in[13];
  float* out = (float*)d_out;
  (void)in_sizes; (void)n_in; (void)out_size;

  char* ws = (char*)d_ws;
  size_t off = 0;
  auto alloc = [&](size_t bytes) -> void* {
    void* p = ws + off; off += (bytes + 255) & ~(size_t)255; return p;
  };
  u16* qbf  = (u16*)alloc((size_t)BB*SS*DD*2);   // q, then reused as bf16 attention-out
  u16* kbf  = (u16*)alloc((size_t)BB*TT*DD*2);
  u16* vT   = (u16*)alloc((size_t)BB*DD*TT*2);
  u16* Xbf  = (u16*)alloc((size_t)BB*SS*DD*2);
  u16* Wqbf = (u16*)alloc((size_t)DD*DD*2);
  float* sv  = (float*)alloc(DD*4);
  uint32_t* m32 = (uint32_t*)alloc((size_t)SS*64*4);
  u16* Sbuf = (u16*)alloc((size_t)BB*SS*TT*2);

  prep_sv<<<DD, 256, 0, stream>>>(Wov, bov, vs, sv);
  // fused: scale_kv_transpose (4096) + cvt X/Wq (4096) + mask_pack (512)
  prep_fused<<<dim3(8704), 256, 0, stream>>>(Y, ks, sv, kbf, vT,
                                             X, Xbf, Wq, Wqbf, mask, m32);

  // Q-proj: 128^2 tile, 128x8 = 1024 blocks
  gemm128_bt<2><<<dim3(1024), 256, 0, stream>>>(Xbf, Wqbf, qbf, bq,
      DD, DD, DD, DD, 8, 1024);
  ln_q<<<(BB*SS)/4, 256, 0, stream>>>(qbf, g1, b1, qs);

  // QK^T: 256^2, 512 blocks; chunk 64 = one batch/XCD
  gemm256_bt<3><<<dim3(512), 512, 0, stream>>>(
      qbf, kbf, Sbuf, nullptr, m32,
      DD, DD, DD, TT,
      (size_t)SS*DD, (size_t)TT*DD, (size_t)SS*TT, 8, 64, 512);

  // PV: 256^2, 256 blocks; bf16 out into qbf (dead after QK^T)
  gemm256_bt<4><<<dim3(256), 512, 0, stream>>>(
      Sbuf, vT, qbf, nullptr, nullptr,
      TT, TT, TT, DD,
      (size_t)SS*TT, (size_t)DD*TT, (size_t)SS*DD, 4, 32, 256);

  final_ln<<<(BB*SS)/4, 256, 0, stream>>>(Xbf, qbf, out, g2, b2);
}

// Round 19
// 279.906 us; speedup vs baseline: 1.0302x; 1.0302x over previous
//
#include <hip/hip_runtime.h>
#include <stdint.h>

typedef unsigned short u16;
typedef __bf16 bf16x8 __attribute__((ext_vector_type(8)));
typedef float f32x4v __attribute__((ext_vector_type(4)));

#define BB 8
#define SS 2048
#define TT 2048
#define DD 1024
#define LN_EPS 1e-5f

__device__ __forceinline__ float sigm(float x){ return 1.f/(1.f+__expf(-x)); }

__device__ __forceinline__ u16 f2bf(float v){
  uint32_t x = __builtin_bit_cast(uint32_t, v);
  uint32_t r = x + 0x7fffu + ((x >> 16) & 1u);
  return (u16)(r >> 16);
}
__device__ __forceinline__ float bf2f(u16 u){
  return __builtin_bit_cast(float, (uint32_t)u << 16);
}

__device__ __forceinline__ void gload16(const void* g, void* l){
  __builtin_amdgcn_global_load_lds((const __attribute__((address_space(1))) unsigned int*)g,
                                   (__attribute__((address_space(3))) unsigned int*)l, 16, 0, 0);
}

__device__ __forceinline__ int xcd_swizzle(int orig, int nwg){
  int q = nwg >> 3, r = nwg & 7;
  int xcd = orig & 7, idx = orig >> 3;
  return (xcd < r ? xcd*(q+1) : r*(q+1) + (xcd-r)*q) + idx;
}

// ---------------- prep: sv[d] = sigm(Wov[d]·sigm(vs)+bov[d]) * tanh(Wov[D+d]·sigm(vs)+bov[D+d]) ----
__global__ __launch_bounds__(256) void prep_sv(const float* __restrict__ Wov, const float* __restrict__ bov,
                        const float* __restrict__ vs, float* __restrict__ sv){
  int d = blockIdx.x, tid = threadIdx.x;
  float a = 0.f, b = 0.f;
  for (int j = tid; j < DD; j += 256){
    float s = sigm(vs[j]);
    a += Wov[(size_t)d*DD + j]*s;
    b += Wov[(size_t)(d+DD)*DD + j]*s;
  }
  #pragma unroll
  for (int o = 32; o; o >>= 1){ a += __shfl_xor(a,o); b += __shfl_xor(b,o); }
  __shared__ float sa[4], sb[4];
  int lane = tid & 63, w = tid >> 6;
  if (!lane){ sa[w] = a; sb[w] = b; }
  __syncthreads();
  if (tid == 0){
    float A = sa[0]+sa[1]+sa[2]+sa[3] + bov[d];
    float Bv= sb[0]+sb[1]+sb[2]+sb[3] + bov[DD+d];
    sv[d] = sigm(A) * tanhf(Bv);
  }
}

// ---------------- merged f32->bf16 for X (n1 elems) and Wq (n2 elems) ----------------
__global__ void cvt_bf16_2(const float* __restrict__ s1, u16* __restrict__ d1, int n1,
                           const float* __restrict__ s2, u16* __restrict__ d2, int n2){
  int n = n1 + n2;
  for (int i = (blockIdx.x*blockDim.x + threadIdx.x)*4; i < n; i += gridDim.x*blockDim.x*4){
    const float* s; u16* d; int j;
    if (i < n1){ s = s1; d = d1; j = i; } else { s = s2; d = d2; j = i - n1; }
    float4 v = *(const float4*)(s + j);
    ushort4 o; o.x = f2bf(v.x); o.y = f2bf(v.y); o.z = f2bf(v.z); o.w = f2bf(v.w);
    *(ushort4*)(d + j) = o;
  }
}

// reads Y once: writes k = bf16(Y*sigm(ks)) row-major AND vT = bf16(Y*sv) transposed
__global__ __launch_bounds__(256) void scale_kv_transpose(const float* __restrict__ Y,
                            const float* __restrict__ ks, const float* __restrict__ sv,
                            u16* __restrict__ kbf, u16* __restrict__ vT){
  __shared__ float tile[64][65];
  int tx = threadIdx.x & 15, ty = threadIdx.x >> 4;
  int b = blockIdx.z;
  int t0 = blockIdx.x*64, d0 = blockIdx.y*64;
  const float* Yb = Y + ((size_t)b*TT + t0)*DD + d0;
  u16* kb = kbf + ((size_t)b*TT + t0)*DD + d0;
  float4 s = *(const float4*)(sv + d0 + tx*4);
  float4 k4 = *(const float4*)(ks + d0 + tx*4);
  k4.x = sigm(k4.x); k4.y = sigm(k4.y); k4.z = sigm(k4.z); k4.w = sigm(k4.w);
  #pragma unroll
  for (int it = 0; it < 4; ++it){
    int t = ty + it*16;
    float4 y = *(const float4*)(Yb + (size_t)t*DD + tx*4);
    ushort4 ko;
    ko.x = f2bf(y.x*k4.x); ko.y = f2bf(y.y*k4.y); ko.z = f2bf(y.z*k4.z); ko.w = f2bf(y.w*k4.w);
    *(ushort4*)(kb + (size_t)t*DD + tx*4) = ko;
    tile[t][tx*4+0] = y.x*s.x; tile[t][tx*4+1] = y.y*s.y;
    tile[t][tx*4+2] = y.z*s.z; tile[t][tx*4+3] = y.w*s.w;
  }
  __syncthreads();
  u16* ob = vT + ((size_t)b*DD + d0)*TT + t0;
  #pragma unroll
  for (int it = 0; it < 4; ++it){
    int dd = ty + it*16;
    ushort4 o;
    o.x = f2bf(tile[tx*4+0][dd]); o.y = f2bf(tile[tx*4+1][dd]);
    o.z = f2bf(tile[tx*4+2][dd]); o.w = f2bf(tile[tx*4+3][dd]);
    *(ushort4*)(ob + (size_t)dd*TT + tx*4) = o;
  }
}

// ---------------- pack mask to bits: m32[r][c32] ----------------
__global__ __launch_bounds__(256) void mask_pack(const int* __restrict__ mask, uint32_t* __restrict__ m32){
  int idx = blockIdx.x*256 + threadIdx.x;
  const int* mp = mask + ((size_t)(idx >> 6))*TT + (idx & 63)*32;
  uint32_t b = 0;
  #pragma unroll
  for (int j = 0; j < 8; ++j){
    int4 v = *(const int4*)(mp + j*4);
    b |= (uint32_t)(v.x != 0) << (j*4+0);
    b |= (uint32_t)(v.y != 0) << (j*4+1);
    b |= (uint32_t)(v.z != 0) << (j*4+2);
    b |= (uint32_t)(v.w != 0) << (j*4+3);
  }
  m32[idx] = b;
}

// ------- 256x256 GEMM, BK=64, 4-phase max-lead counted-vmcnt pipeline (verified) -------
// OUTMODE: 3=bf16 exp+mask (QK^T), 4=bf16 row-normalized (PV)
template<int OUTMODE>
__global__ __launch_bounds__(512, 1)
void gemm256_bt(const u16* __restrict__ A, const u16* __restrict__ B,
                void* __restrict__ Cv, const float* __restrict__ bias,
                const uint32_t* __restrict__ mpk,
                int K, int lda, int ldb, int ldc,
                size_t sA, size_t sB, size_t sC, int ntx, int ntxty, int nwg)
{
  __shared__ __align__(16) u16 As[2][16384];
  __shared__ __align__(16) u16 Bs[2][16384];
  __shared__ float Lsum[256];
  const int tid = threadIdx.x, lane = tid & 63, w = tid >> 6;
  const int wm = w >> 2, wn = w & 3;
  const int sw = xcd_swizzle(blockIdx.x, nwg);
  const int bz_ = sw / ntxty;
  const int rem = sw - bz_*ntxty;
  const int by = rem / ntx, bx = rem - (rem/ntx)*ntx;
  const size_t bz = bz_;
  const int tM = by*256, tN = bx*256;
  const u16* Ab = A + bz*sA;
  const u16* Bb = B + bz*sB;
  const int NT = K >> 6;

  const int srow  = lane >> 3;
  const int sslot = (lane & 7) ^ srow;
  const int frow  = lane & 15;
  const int fs    = lane >> 4;
  const int fx    = lane & 7;

#define BAR() asm volatile("s_barrier" ::: "memory")
#define WAITV(n) asm volatile("s_waitcnt vmcnt(" #n ")" ::: "memory")

#define STAGE(h) do { \
    const int tau_ = (h) >> 2, typ_ = (h) & 3; \
    const int buf_ = tau_ & 1, hi_ = typ_ >> 1, k0_ = tau_ << 6; \
    const u16* src_; int ld_, t0_; u16* dst_; \
    if ((typ_ & 1) == 0){ src_ = Ab; ld_ = lda; t0_ = tM; dst_ = &As[buf_][hi_*8192]; } \
    else                { src_ = Bb; ld_ = ldb; t0_ = tN; dst_ = &Bs[buf_][hi_*8192]; } \
    _Pragma("unroll") \
    for (int i_ = 0; i_ < 2; ++i_){ \
      const int chunk_ = w*2 + i_; \
      gload16(src_ + (size_t)(t0_ + hi_*128 + chunk_*8 + srow)*ld_ + (k0_ + sslot*8), \
              dst_ + chunk_*512); \
    } } while(0)

#define READA(buf, mh, a) do { \
    _Pragma("unroll") for (int m_ = 0; m_ < 4; ++m_) \
    _Pragma("unroll") for (int ks_ = 0; ks_ < 2; ++ks_) \
      a[m_*2+ks_] = *(const bf16x8*)&As[buf][(wm*128 + (mh)*64 + m_*16 + frow)*64 + ((ks_*4+fs)^fx)*8]; \
  } while(0)
#define READB(buf, nh, b) do { \
    _Pragma("unroll") for (int n_ = 0; n_ < 2; ++n_) \
    _Pragma("unroll") for (int ks_ = 0; ks_ < 2; ++ks_) \
      b[n_*2+ks_] = *(const bf16x8*)&Bs[buf][(wn*64 + (nh)*32 + n_*16 + frow)*64 + ((ks_*4+fs)^fx)*8]; \
  } while(0)
#define QUAD(mh, nh, a, b) do { \
    __builtin_amdgcn_s_setprio(1); \
    _Pragma("unroll") for (int m_ = 0; m_ < 4; ++m_) \
    _Pragma("unroll") for (int n_ = 0; n_ < 2; ++n_) \
    _Pragma("unroll") for (int ks_ = 0; ks_ < 2; ++ks_) \
      acc[(mh)*4+m_][(nh)*2+n_] = __builtin_amdgcn_mfma_f32_16x16x32_bf16( \
          a[m_*2+ks_], b[n_*2+ks_], acc[(mh)*4+m_][(nh)*2+n_], 0, 0, 0); \
    __builtin_amdgcn_s_setprio(0); \
  } while(0)
#define LSUM(mh, a) do { \
    if (OUTMODE == 4 && wn == (mh)){ \
      _Pragma("unroll") for (int m_ = 0; m_ < 4; ++m_){ \
        acc_l[m_] = __builtin_amdgcn_mfma_f32_16x16x32_bf16(a[m_*2],   vone, acc_l[m_], 0, 0, 0); \
        acc_l[m_] = __builtin_amdgcn_mfma_f32_16x16x32_bf16(a[m_*2+1], vone, acc_l[m_], 0, 0, 0); \
      } \
    } } while(0)

  f32x4v acc[8][4];
  #pragma unroll
  for (int m = 0; m < 8; ++m)
    #pragma unroll
    for (int n = 0; n < 4; ++n) acc[m][n] = (f32x4v){0.f,0.f,0.f,0.f};

  f32x4v acc_l[4];
  bf16x8 vone;
  #pragma unroll
  for (int m = 0; m < 4; ++m) acc_l[m] = (f32x4v){0.f,0.f,0.f,0.f};
  #pragma unroll
  for (int i = 0; i < 8; ++i) vone[i] = (__bf16)1.0f;

  #pragma unroll
  for (int h = 0; h < 8; ++h) STAGE(h);

  bf16x8 a0[8], a1[8], b0[4], b1[4];

  for (int t = 0; t < NT; ++t){
    const int buf = t & 1;
    const int nx = t + 2;
    if (t == NT-1) { WAITV(0); } else { WAITV(8); }
    BAR();
    READA(buf, 0, a0);
    READB(buf, 0, b0);
    QUAD(0, 0, a0, b0);
    LSUM(0, a0);
    BAR();
    READB(buf, 1, b1);
    QUAD(0, 1, a0, b1);
    BAR();
    READA(buf, 1, a1);
    if (nx < NT){ STAGE(nx*4+1); STAGE(nx*4+3); }
    QUAD(1, 1, a1, b1);
    LSUM(1, a1);
    BAR();
    if (nx < NT){ STAGE(nx*4+0); STAGE(nx*4+2); }
    QUAD(1, 0, a1, b0);
  }

  const int erow = (lane >> 4) * 4;
  const int ecol = lane & 15;

  if (OUTMODE == 4){
    if (wn < 2 && ecol == 0){
      #pragma unroll
      for (int m = 0; m < 4; ++m)
        #pragma unroll
        for (int r = 0; r < 4; ++r)
          Lsum[wm*128 + wn*64 + m*16 + erow + r] = acc_l[m][r];
    }
    __syncthreads();
  }

  #pragma unroll
  for (int m = 0; m < 8; ++m){
    float li[4];
    if (OUTMODE == 4){
      #pragma unroll
      for (int r = 0; r < 4; ++r) li[r] = 1.f / Lsum[wm*128 + m*16 + erow + r];
    }
    #pragma unroll
    for (int n = 0; n < 4; ++n){
      const int row0 = tM + wm*128 + m*16 + erow;
      const int col  = tN + wn*64  + n*16 + ecol;
      if (OUTMODE == 4){
        u16* C = (u16*)Cv + bz*sC;
        #pragma unroll
        for (int r = 0; r < 4; ++r) C[(size_t)(row0+r)*ldc + col] = f2bf(acc[m][n][r] * li[r]);
      } else {
        u16* C = (u16*)Cv + bz*sC;
        const int c32 = (tN + wn*64 + n*16) >> 5;
        #pragma unroll
        for (int r = 0; r < 4; ++r){
          const int row = row0 + r;
          const uint32_t mb = mpk[(size_t)row*64 + c32];
          float e = ((mb >> (col & 31)) & 1u) ? __expf(acc[m][n][r]) : 0.f;
          C[(size_t)row*ldc + col] = f2bf(e);
        }
      }
    }
  }
#undef STAGE
#undef READA
#undef READB
#undef QUAD
#undef LSUM
#undef BAR
#undef WAITV
}

// ------- 128x128 GEMM, BK=64, same 4-phase dbuf pipeline, 4 waves (verified) -------
template<int OUTMODE>
__global__ __launch_bounds__(256, 1)
void gemm128_bt(const u16* __restrict__ A, const u16* __restrict__ B,
                void* __restrict__ Cv, const float* __restrict__ bias,
                int K, int lda, int ldb, int ldc, int ntx, int nwg)
{
  __shared__ __align__(16) u16 As[2][8192];
  __shared__ __align__(16) u16 Bs[2][8192];
  const int tid = threadIdx.x, lane = tid & 63, w = tid >> 6;
  const int wm = w >> 1, wn = w & 1;
  const int sw = xcd_swizzle(blockIdx.x, nwg);
  const int by = sw / ntx, bx = sw - (sw/ntx)*ntx;
  const int tM = by*128, tN = bx*128;
  const int NT = K >> 6;

  const int srow  = lane >> 3;
  const int sslot = (lane & 7) ^ srow;
  const int frow  = lane & 15;
  const int fs    = lane >> 4;
  const int fx    = lane & 7;

#define BAR() asm volatile("s_barrier" ::: "memory")
#define WAITV(n) asm volatile("s_waitcnt vmcnt(" #n ")" ::: "memory")

#define STAGE(h) do { \
    const int tau_ = (h) >> 2, typ_ = (h) & 3; \
    const int buf_ = tau_ & 1, hi_ = typ_ >> 1, k0_ = tau_ << 6; \
    const u16* src_; int ld_, t0_; u16* dst_; \
    if ((typ_ & 1) == 0){ src_ = A; ld_ = lda; t0_ = tM; dst_ = &As[buf_][hi_*4096]; } \
    else                { src_ = B; ld_ = ldb; t0_ = tN; dst_ = &Bs[buf_][hi_*4096]; } \
    _Pragma("unroll") \
    for (int i_ = 0; i_ < 2; ++i_){ \
      const int chunk_ = w*2 + i_; \
      gload16(src_ + (size_t)(t0_ + hi_*64 + chunk_*8 + srow)*ld_ + (k0_ + sslot*8), \
              dst_ + chunk_*512); \
    } } while(0)

#define READA(buf, mh, a) do { \
    _Pragma("unroll") for (int m_ = 0; m_ < 2; ++m_) \
    _Pragma("unroll") for (int ks_ = 0; ks_ < 2; ++ks_) \
      a[m_*2+ks_] = *(const bf16x8*)&As[buf][(wm*64 + (mh)*32 + m_*16 + frow)*64 + ((ks_*4+fs)^fx)*8]; \
  } while(0)
#define READB(buf, nh, b) do { \
    _Pragma("unroll") for (int n_ = 0; n_ < 2; ++n_) \
    _Pragma("unroll") for (int ks_ = 0; ks_ < 2; ++ks_) \
      b[n_*2+ks_] = *(const bf16x8*)&Bs[buf][(wn*64 + (nh)*32 + n_*16 + frow)*64 + ((ks_*4+fs)^fx)*8]; \
  } while(0)
#define QUAD(mh, nh, a, b) do { \
    __builtin_amdgcn_s_setprio(1); \
    _Pragma("unroll") for (int m_ = 0; m_ < 2; ++m_) \
    _Pragma("unroll") for (int n_ = 0; n_ < 2; ++n_) \
    _Pragma("unroll") for (int ks_ = 0; ks_ < 2; ++ks_) \
      acc[(mh)*2+m_][(nh)*2+n_] = __builtin_amdgcn_mfma_f32_16x16x32_bf16( \
          a[m_*2+ks_], b[n_*2+ks_], acc[(mh)*2+m_][(nh)*2+n_], 0, 0, 0); \
    __builtin_amdgcn_s_setprio(0); \
  } while(0)

  f32x4v acc[4][4];
  #pragma unroll
  for (int m = 0; m < 4; ++m)
    #pragma unroll
    for (int n = 0; n < 4; ++n) acc[m][n] = (f32x4v){0.f,0.f,0.f,0.f};

  #pragma unroll
  for (int h = 0; h < 8; ++h) STAGE(h);

  bf16x8 a0[4], a1[4], b0[4], b1[4];

  for (int t = 0; t < NT; ++t){
    const int buf = t & 1;
    const int nx = t + 2;
    if (t == NT-1) { WAITV(0); } else { WAITV(8); }
    BAR();
    READA(buf, 0, a0);
    READB(buf, 0, b0);
    QUAD(0, 0, a0, b0);
    BAR();
    READB(buf, 1, b1);
    QUAD(0, 1, a0, b1);
    BAR();
    READA(buf, 1, a1);
    if (nx < NT){ STAGE(nx*4+1); STAGE(nx*4+3); }
    QUAD(1, 1, a1, b1);
    BAR();
    if (nx < NT){ STAGE(nx*4+0); STAGE(nx*4+2); }
    QUAD(1, 0, a1, b0);
  }

  const int erow = (lane >> 4) * 4;
  const int ecol = lane & 15;
  #pragma unroll
  for (int m = 0; m < 4; ++m){
    #pragma unroll
    for (int n = 0; n < 4; ++n){
      const int row0 = tM + wm*64 + m*16 + erow;
      const int col  = tN + wn*64 + n*16 + ecol;
      float bv = (OUTMODE == 2) ? bias[col] : 0.f;
      u16* C = (u16*)Cv;
      #pragma unroll
      for (int r = 0; r < 4; ++r) C[(size_t)(row0+r)*ldc + col] = f2bf(acc[m][n][r] + bv);
    }
  }
#undef STAGE
#undef READA
#undef READB
#undef QUAD
#undef BAR
#undef WAITV
}

// ---------------- per-wave LN on q rows (bf16 in-place), sigm(qs) inline ----------------
__global__ __launch_bounds__(256) void ln_q(u16* __restrict__ qb, const float* __restrict__ g1,
                     const float* __restrict__ b1, const float* __restrict__ qs){
  const int w = threadIdx.x >> 6, lane = threadIdx.x & 63;
  const size_t r = (size_t)blockIdx.x * 4 + w;
  u16* row = qb + r * DD;
  uint4 v0 = *(const uint4*)(row + lane*16);
  uint4 v1 = *(const uint4*)(row + lane*16 + 8);
  const u16* vp0 = (const u16*)&v0;
  const u16* vp1 = (const u16*)&v1;
  float x[16];
  #pragma unroll
  for (int i = 0; i < 8; ++i){ x[i] = bf2f(vp0[i]); x[8+i] = bf2f(vp1[i]); }
  float s = 0.f, ss = 0.f;
  #pragma unroll
  for (int i = 0; i < 16; ++i){ s += x[i]; ss += x[i]*x[i]; }
  #pragma unroll
  for (int o = 32; o; o >>= 1){ s += __shfl_xor(s,o); ss += __shfl_xor(ss,o); }
  float mean = s * (1.f/DD);
  float var  = ss * (1.f/DD) - mean*mean;
  float rs = rsqrtf(var + LN_EPS);
  uint4 o0, o1;
  u16* op0 = (u16*)&o0; u16* op1 = (u16*)&o1;
  #pragma unroll
  for (int j = 0; j < 4; ++j){
    float4 g = *(const float4*)(g1 + lane*16 + j*4);
    float4 b = *(const float4*)(b1 + lane*16 + j*4);
    float4 q = *(const float4*)(qs + lane*16 + j*4);
    q.x = sigm(q.x); q.y = sigm(q.y); q.z = sigm(q.z); q.w = sigm(q.w);
    u16* op = (j < 2) ? (op0 + j*4) : (op1 + (j-2)*4);
    op[0] = f2bf(((x[j*4+0]-mean)*rs*g.x + b.x) * q.x * 0.03125f);
    op[1] = f2bf(((x[j*4+1]-mean)*rs*g.y + b.y) * q.y * 0.03125f);
    op[2] = f2bf(((x[j*4+2]-mean)*rs*g.z + b.z) * q.z * 0.03125f);
    op[3] = f2bf(((x[j*4+3]-mean)*rs*g.w + b.w) * q.w * 0.03125f);
  }
  *(uint4*)(row + lane*16) = o0;
  *(uint4*)(row + lane*16 + 8) = o1;
}

// ------- per-wave final LN: reads Xbf (bf16) + obf (bf16), writes d_out f32 once -------
__global__ __launch_bounds__(256) void final_ln(const u16* __restrict__ Xbf, const u16* __restrict__ obf,
                         float* __restrict__ out,
                         const float* __restrict__ g2, const float* __restrict__ b2){
  const int w = threadIdx.x >> 6, lane = threadIdx.x & 63;
  const size_t r = (size_t)blockIdx.x * 4 + w;
  const u16* xr = Xbf + r * DD;
  const u16* orr = obf + r * DD;
  float* orw = out + r * DD;
  uint4 xv0 = *(const uint4*)(xr + lane*16);
  uint4 xv1 = *(const uint4*)(xr + lane*16 + 8);
  uint4 ov0 = *(const uint4*)(orr + lane*16);
  uint4 ov1 = *(const uint4*)(orr + lane*16 + 8);
  const u16* xp0 = (const u16*)&xv0;
  const u16* xp1 = (const u16*)&xv1;
  const u16* op0 = (const u16*)&ov0;
  const u16* op1 = (const u16*)&ov1;
  float z[16];
  float s = 0.f, ss = 0.f;
  #pragma unroll
  for (int i = 0; i < 8; ++i){
    z[i]   = bf2f(xp0[i]) + bf2f(op0[i]);
    z[8+i] = bf2f(xp1[i]) + bf2f(op1[i]);
  }
  #pragma unroll
  for (int i = 0; i < 16; ++i){ s += z[i]; ss += z[i]*z[i]; }
  #pragma unroll
  for (int o = 32; o; o >>= 1){ s += __shfl_xor(s,o); ss += __shfl_xor(ss,o); }
  float mean = s * (1.f/DD);
  float var  = ss * (1.f/DD) - mean*mean;
  float rs = rsqrtf(var + LN_EPS);
  #pragma unroll
  for (int j = 0; j < 4; ++j){
    float4 g = *(const float4*)(g2 + lane*16 + j*4);
    float4 b = *(const float4*)(b2 + lane*16 + j*4);
    float4 o;
    o.x = (z[j*4+0]-mean)*rs*g.x + b.x;
    o.y = (z[j*4+1]-mean)*rs*g.y + b.y;
    o.z = (z[j*4+2]-mean)*rs*g.z + b.z;
    o.w = (z[j*4+3]-mean)*rs*g.w + b.w;
    *(float4*)(orw + lane*16 + j*4) = o;
  }
}

extern "C" void kernel_launch(void* const* d_in, const int* in_sizes, int n_in,
                              void* d_out, int out_size, void* d_ws, size_t ws_size,
                              hipStream_t stream)
{
  const float* X  = (const float*)d_in[0];
  const float* Y  = (const float*)d_in[1];
  const float* qs = (const float*)d_in[2];
  const float* ks = (const float*)d_in[3];
  const float* vs = (const float*)d_in[4];
  const float* Wq = (const float*)d_in[5];
  const float* bq = (const float*)d_in[6];
  const float* g1 = (const float*)d_in[7];
  const float* b1 = (const float*)d_in[8];
  const float* Wov= (const float*)d_in[9];
  const float* bov= (const float*)d_in[10];
  const float* g2 = (const float*)d_in[11];
  const float* b2 = (const float*)d_in[12];
  const int* mask = (const int*)d_in[13];
  float* out = (float*)d_out;
  (void)in_sizes; (void)n_in; (void)out_size;

  char* ws = (char*)d_ws;
  size_t off = 0;
  auto alloc = [&](size_t bytes) -> void* {
    void* p = ws + off; off += (bytes + 255) & ~(size_t)255; return p;
  };
  u16* qbf  = (u16*)alloc((size_t)BB*SS*DD*2);   // q, then reused as bf16 attention-out
  u16* kbf  = (u16*)alloc((size_t)BB*TT*DD*2);
  u16* vT   = (u16*)alloc((size_t)BB*DD*TT*2);
  u16* Xbf  = (u16*)alloc((size_t)BB*SS*DD*2);
  u16* Wqbf = (u16*)alloc((size_t)DD*DD*2);
  float* sv  = (float*)alloc(DD*4);
  uint32_t* m32 = (uint32_t*)alloc((size_t)SS*64*4);
  u16* Sbuf = (u16*)alloc((size_t)BB*SS*TT*2);

  prep_sv<<<DD, 256, 0, stream>>>(Wov, bov, vs, sv);
  cvt_bf16_2<<<4096, 256, 0, stream>>>(X, Xbf, BB*SS*DD, Wq, Wqbf, DD*DD);
  dim3 tg(TT/64, DD/64, BB);
  scale_kv_transpose<<<tg, 256, 0, stream>>>(Y, ks, sv, kbf, vT);
  mask_pack<<<(SS*64)/256, 256, 0, stream>>>(mask, m32);

  // Q-proj: 128^2 tile, 128x8 = 1024 blocks
  gemm128_bt<2><<<dim3(1024), 256, 0, stream>>>(Xbf, Wqbf, qbf, bq,
      DD, DD, DD, DD, 8, 1024);
  ln_q<<<(BB*SS)/4, 256, 0, stream>>>(qbf, g1, b1, qs);

  // QK^T: 256^2, 512 blocks; chunk 64 = one batch/XCD
  gemm256_bt<3><<<dim3(512), 512, 0, stream>>>(
      qbf, kbf, Sbuf, nullptr, m32,
      DD, DD, DD, TT,
      (size_t)SS*DD, (size_t)TT*DD, (size_t)SS*TT, 8, 64, 512);

  // PV: 256^2, 256 blocks; bf16 out into qbf (dead after QK^T)
  gemm256_bt<4><<<dim3(256), 512, 0, stream>>>(
      Sbuf, vT, qbf, nullptr, nullptr,
      TT, TT, TT, DD,
      (size_t)SS*TT, (size_t)DD*TT, (size_t)SS*DD, 4, 32, 256);

  final_ln<<<(BB*SS)/4, 256, 0, stream>>>(Xbf, qbf, out, g2, b2);
}